// Round 12
// baseline (136.464 us; speedup 1.0000x reference)
//
#include <hip/hip_runtime.h>
#include <hip/hip_bf16.h>
#include <math.h>

#define KN 20
#define DD 64
#define WPB 4
#define NUSERS 100000
#define NITEMS 50000
#define UGROUPS 1563   // ceil(100000/64)
#define IGROUPS 782    // ceil(50000/64)
#define TGROUPS (UGROUPS + IGROUPS)          // 2345 waves of Y work
#define NBY 587        // ceil(TGROUPS/4) Y blocks
#define NBS 128        // score-convert blocks (only when ws is big enough)
#define SROW 24        // padded bf16 score row stride (48B, zeros 20..23)

typedef __hip_bfloat16 bf16;
typedef __attribute__((ext_vector_type(8))) short short8;   // 8 bf16 (4 VGPRs)
typedef __attribute__((ext_vector_type(16))) float f32x16;  // MFMA 32x32 acc

__device__ inline ushort f2bf(float f) {                    // fp32 -> bf16 RNE
    unsigned u = __builtin_bit_cast(unsigned, f);
    u += 0x7fffu + ((u >> 16) & 1u);
    return (ushort)(u >> 16);
}

// ====== precompute: Y = emb @ W1part; w2 -> frag table; scores -> bf16 ========
// Y-compute REWRITE (R11 was DS-pipe-bound: 64 broadcast ds_read_b128 per
// 4-row group ~= 47us). Now lane = row: w1[c][o] is wave-uniform -> s_load
// (SMEM pipe); emb[row][c] per-lane float4; acc[64] in VGPRs (compile-time
// indices only); ZERO DS ops. cq loop kept rolled (code ~2.5KB, icache-safe).
__global__ __launch_bounds__(256, 4) void precompute_Y(
    const float* __restrict__ emb_u, const float* __restrict__ emb_i,
    const float* __restrict__ w1, const float* __restrict__ w2,
    const float* __restrict__ uscr, const float* __restrict__ iscr,
    bf16* __restrict__ Yu, bf16* __restrict__ Yi, ushort* __restrict__ w2b,
    ushort* __restrict__ sbu, ushort* __restrict__ sbi)
{
    const int w    = threadIdx.x >> 6;
    const int lane = threadIdx.x & 63;
    const int bid  = (int)blockIdx.x;

    // ---- score tables -> bf16, chunk-parallel (1 thread = one 16B out chunk) --
    if (bid >= NBY) {
        const int t0 = (bid - NBY) * 256 + (int)threadIdx.x;
        const int NCH = 3 * (NUSERS + NITEMS);
        for (int cch = t0; cch < NCH; cch += NBS * 256) {
            int r = cch / 3, part = cch - 3 * r;
            const float* src = (r < NUSERS) ? (uscr + (size_t)r * KN)
                                            : (iscr + (size_t)(r - NUSERS) * KN);
            ushort* dst = (r < NUSERS) ? (sbu + (size_t)r * SROW)
                                       : (sbi + (size_t)(r - NUSERS) * SROW);
            ushort tmp[8];
            if (part < 2) {
                float4 v0 = *(const float4*)(src + 8 * part);
                float4 v1 = *(const float4*)(src + 8 * part + 4);
                tmp[0] = f2bf(v0.x); tmp[1] = f2bf(v0.y);
                tmp[2] = f2bf(v0.z); tmp[3] = f2bf(v0.w);
                tmp[4] = f2bf(v1.x); tmp[5] = f2bf(v1.y);
                tmp[6] = f2bf(v1.z); tmp[7] = f2bf(v1.w);
            } else {
                float4 v0 = *(const float4*)(src + 16);
                tmp[0] = f2bf(v0.x); tmp[1] = f2bf(v0.y);
                tmp[2] = f2bf(v0.z); tmp[3] = f2bf(v0.w);
                tmp[4] = tmp[5] = tmp[6] = tmp[7] = 0;
            }
            *(short8*)(dst + 8 * part) = *(const short8*)tmp;
        }
        return;
    }

    // ---- w2 -> MFMA-B fragment order (always runs; last Y block) ----
    if (bid == NBY - 1) {
        const int tid = threadIdx.x;
        const int t = tid >> 6, gg = (tid >> 5) & 1, o = tid & 31;
        #pragma unroll
        for (int j = 0; j < 8; ++j)
            w2b[(size_t)tid * 8 + j] = f2bf(w2[(16 * t + 8 * gg + j) * 32 + o]);
    }

    // ---- Y compute: one wave per 64-row group, lane = row ----
    const int g = bid * WPB + w;
    if (g >= TGROUPS) return;
    const bool isU = g < UGROUPS;
    const float* __restrict__ emb  = isU ? emb_u : emb_i;
    bf16* __restrict__        Y    = isU ? Yu : Yi;
    const float* __restrict__ wsrc = isU ? w1 : (w1 + 64 * DD);
    const int nrows = isU ? NUSERS : NITEMS;
    int row = (isU ? g : (g - UGROUPS)) * 64 + lane;
    if (row >= nrows) row = nrows - 1;     // clamped lanes duplicate last row (benign)

    const float* __restrict__ er = emb + (size_t)row * DD;
    float acc[64];
    #pragma unroll
    for (int o = 0; o < 64; ++o) acc[o] = 0.f;

    for (int cq = 0; cq < 16; ++cq) {      // rolled: code size, dynamic uniform addr
        float4 e4 = *(const float4*)(er + cq * 4);
        #pragma unroll
        for (int cc = 0; cc < 4; ++cc) {
            const float ev = (cc == 0) ? e4.x : (cc == 1) ? e4.y : (cc == 2) ? e4.z : e4.w;
            const float* __restrict__ wr = wsrc + (cq * 4 + cc) * DD;  // uniform -> s_load
            #pragma unroll
            for (int o = 0; o < 64; ++o)
                acc[o] = fmaf(ev, wr[o], acc[o]);
        }
    }

    ushort* yrow = (ushort*)Y + (size_t)row * DD;
    #pragma unroll
    for (int q = 0; q < 8; ++q) {
        ushort tmp[8];
        #pragma unroll
        for (int j = 0; j < 8; ++j) tmp[j] = f2bf(acc[q * 8 + j]);
        *(short8*)(yrow + q * 8) = *(const short8*)tmp;
    }
}

// ================= main fused kernel (unchanged from R11) =====================
// GEMM1 on MFMA (R8/R9 verified layouts); Y rows staged via wave-private LDS;
// B-frags = ds_read_u16 w/ offset immediates; A-frags = direct 16B loads from
// pre-converted bf16 score tables (SBF). h1 (bf16, XOR-swizzled) unions into
// the user staging region; all LDS wave-private -> barrier-free.
template<bool SBF>
__global__ __launch_bounds__(256, 8) void cnn_main(
    const int* __restrict__ user_idxs, const int* __restrict__ item_idxs,
    const int* __restrict__ user_idx_tensor, const float* __restrict__ uscr_f,
    const ushort* __restrict__ uscr_b,
    const int* __restrict__ item_idx_tensor, const float* __restrict__ iscr_f,
    const ushort* __restrict__ iscr_b,
    const bf16* __restrict__ Yu, const bf16* __restrict__ Yi,
    const float* __restrict__ b1, const ushort* __restrict__ w2b,
    const float* __restrict__ b2,
    const float* __restrict__ w3, const float* __restrict__ b3,
    float* __restrict__ out, int Bn)
{
    __shared__ ushort buf[WPB][3072];  // [side][24][64] staging; h1 reuses [0..1280)

    const int w    = threadIdx.x >> 6;
    const int lane = threadIdx.x & 63;
    const int g    = lane >> 5;            // half-wave group (k-octet select)
    const int c    = lane & 31;            // tile column / row index
    const int b = blockIdx.x * WPB + w;
    if (b >= Bn) return;                   // no barriers -> divergence-safe

    const int uid = user_idxs[b];
    const int iid = item_idxs[b];

    int nvu = 0, nvi = 0;
    if (lane < KN) {
        nvu = user_idx_tensor[uid * KN + lane];
        nvi = item_idx_tensor[iid * KN + lane];
    }

    // ---- stage Y rows (both sides) into wave-private LDS, coalesced ----
    #pragma unroll
    for (int side = 0; side < 2; ++side) {
        const ushort* Y = (const ushort*)(side ? Yi : Yu);
        const int nv = side ? nvi : nvu;
        #pragma unroll
        for (int i = 0; i < 3; ++i) {                 // rows 8i..8i+7 (16..23 pad junk)
            int nr = __shfl(nv, 8 * i + (lane >> 3)); // lanes>=KN give nv=0: safe
            short8 v = *(const short8*)(Y + (size_t)nr * DD + (lane & 7) * 8);
            *(short8*)&buf[w][side * 1536 + i * 512 + lane * 8] = v;
        }
    }

    f32x16 acc0 = {};   // h1 cols 0..31
    f32x16 acc1 = {};   // h1 cols 32..63

    #pragma unroll
    for (int side = 0; side < 2; ++side) {
        const int nv = side ? nvi : nvu;
        const int n_r = __shfl(nv, c);

        // ---- A frags: score row (l&31), k-octet 8g+j ----
        short8 A0, A1;
        if (SBF) {
            const ushort* sr = (side ? iscr_b : uscr_b) + (size_t)n_r * SROW;
            A0 = *(const short8*)(sr + 8 * g);     // k 8g..8g+7
            A1 = *(const short8*)(sr + 16);        // k 16..23 (20..23 are zeros)
        } else {
            const float* arow = (side ? iscr_f : uscr_f) + (size_t)n_r * KN;
            float4 a0 = *(const float4*)(arow + 8 * g);
            float4 a1 = *(const float4*)(arow + 8 * g + 4);
            A0[0] = (short)f2bf(a0.x); A0[1] = (short)f2bf(a0.y);
            A0[2] = (short)f2bf(a0.z); A0[3] = (short)f2bf(a0.w);
            A0[4] = (short)f2bf(a1.x); A0[5] = (short)f2bf(a1.y);
            A0[6] = (short)f2bf(a1.z); A0[7] = (short)f2bf(a1.w);
            float4 a2 = *(const float4*)(arow + 16);
            A1 = short8{};
            A1[0] = (short)f2bf(a2.x); A1[1] = (short)f2bf(a2.y);
            A1[2] = (short)f2bf(a2.z); A1[3] = (short)f2bf(a2.w);
        }

        // ---- B frags from LDS (base reg + offset immediates) ----
        const int sb0 = side * 1536;
        short8 B00, B01;
        #pragma unroll
        for (int j = 0; j < 8; ++j) {
            B00[j] = (short)buf[w][sb0 + (8 * g + j) * DD + c];
            B01[j] = (short)buf[w][sb0 + (8 * g + j) * DD + 32 + c];
        }
        acc0 = __builtin_amdgcn_mfma_f32_32x32x16_bf16(A0, B00, acc0, 0, 0, 0);
        acc1 = __builtin_amdgcn_mfma_f32_32x32x16_bf16(A0, B01, acc1, 0, 0, 0);

        short8 B10 = {}, B11 = {};
        if (g == 0) {                                  // rows 16..19; g1 keeps zeros
            #pragma unroll
            for (int j = 0; j < 4; ++j) {
                B10[j] = (short)buf[w][sb0 + (16 + j) * DD + c];
                B11[j] = (short)buf[w][sb0 + (16 + j) * DD + 32 + c];
            }
        }
        acc0 = __builtin_amdgcn_mfma_f32_32x32x16_bf16(A1, B10, acc0, 0, 0, 0);
        acc1 = __builtin_amdgcn_mfma_f32_32x32x16_bf16(A1, B11, acc1, 0, 0, 0);
    }

    // ---- bias + relu -> bf16 -> swizzled LDS rows<20 (reuses [0..1280)) ----
    const float b1v0 = b1[c];
    const float b1v1 = b1[32 + c];
    #pragma unroll
    for (int r = 0; r < 12; ++r) {
        const int row = (r & 3) + 8 * (r >> 2) + 4 * g;
        if (row < KN) {
            const int ch0 = (c >> 3) ^ (row & 7);
            const int ch1 = (4 + (c >> 3)) ^ (row & 7);
            buf[w][row * DD + ch0 * 8 + (c & 7)] = f2bf(fmaxf(acc0[r] + b1v0, 0.f));
            buf[w][row * DD + ch1 * 8 + (c & 7)] = f2bf(fmaxf(acc1[r] + b1v1, 0.f));
        }
    }

    // ---- layer2 MFMA: h2(20x32) = h1(20x64) @ w2(64x32), 4 K-steps ----
    const int ar = (c < KN) ? c : 0;       // clamp A row (rows>=20 don't-care)
    f32x16 c2 = {};
    #pragma unroll
    for (int t = 0; t < 4; ++t) {
        const int chunk = (2 * t + g) ^ (ar & 7);
        short8 A = *(const short8*)&buf[w][ar * DD + chunk * 8];
        short8 B = *(const short8*)&w2b[(size_t)(((t * 2 + g) * 32 + c)) * 8];
        c2 = __builtin_amdgcn_mfma_f32_32x32x16_bf16(A, B, c2, 0, 0, 0);
    }

    // ---- layer3: bias+relu, *w3, butterfly over 32 cols, sigmoid, mean ----
    const float b2v = b2[c];
    const float w3v = w3[c];
    const float b3v = b3[0];
    float sum = 0.f;
    #pragma unroll
    for (int r = 0; r < 12; ++r) {
        float h2v = fmaxf(c2[r] + b2v, 0.f);
        float p = h2v * w3v;
        #pragma unroll
        for (int off = 16; off > 0; off >>= 1)
            p += __shfl_xor(p, off);               // sum over 32 out-cols
        float logit = p + b3v;
        if (g == 0 || r < 8)                       // valid rows: g0 12, g1 8 (=20)
            sum += 1.f / (1.f + __expf(-logit));
    }
    sum += __shfl_xor(sum, 32);
    if (lane == 0) out[b] = sum * (1.f / KN);
}

extern "C" void kernel_launch(void* const* d_in, const int* in_sizes, int n_in,
                              void* d_out, int out_size, void* d_ws, size_t ws_size,
                              hipStream_t stream) {
    const int*   user_idxs       = (const int*)  d_in[0];
    const int*   item_idxs       = (const int*)  d_in[1];
    const int*   user_idx_tensor = (const int*)  d_in[2];
    const float* user_scr_tensor = (const float*)d_in[3];
    const int*   item_idx_tensor = (const int*)  d_in[4];
    const float* item_scr_tensor = (const float*)d_in[5];
    const float* user_emb        = (const float*)d_in[6];
    const float* item_emb        = (const float*)d_in[7];
    const float* w1 = (const float*)d_in[8];
    const float* b1 = (const float*)d_in[9];
    const float* w2 = (const float*)d_in[10];
    const float* b2 = (const float*)d_in[11];
    const float* w3 = (const float*)d_in[12];
    const float* b3 = (const float*)d_in[13];
    float* out = (float*)d_out;

    const int Bn = in_sizes[0];

    // ws: Yu bf16[100000*64] | Yi bf16[50000*64] | w2b u16[2048] | sbu | sbi
    bf16*   Yu  = (bf16*)d_ws;
    bf16*   Yi  = Yu + (size_t)NUSERS * DD;
    ushort* w2b = (ushort*)(Yi + (size_t)NITEMS * DD);
    ushort* sbu = w2b + 2048;
    ushort* sbi = sbu + (size_t)NUSERS * SROW;

    const size_t need = (size_t)(NUSERS + NITEMS) * DD * 2 + 2048 * 2
                      + (size_t)(NUSERS + NITEMS) * SROW * 2;
    const bool big = ws_size >= need;

    precompute_Y<<<NBY + (big ? NBS : 0), 256, 0, stream>>>(
        user_emb, item_emb, w1, w2, user_scr_tensor, item_scr_tensor,
        Yu, Yi, w2b, sbu, sbi);

    const int grid = (Bn + WPB - 1) / WPB;
    if (big)
        cnn_main<true><<<grid, 256, 0, stream>>>(
            user_idxs, item_idxs, user_idx_tensor, user_scr_tensor, sbu,
            item_idx_tensor, item_scr_tensor, sbi, Yu, Yi,
            b1, w2b, b2, w3, b3, out, Bn);
    else
        cnn_main<false><<<grid, 256, 0, stream>>>(
            user_idxs, item_idxs, user_idx_tensor, user_scr_tensor, sbu,
            item_idx_tensor, item_scr_tensor, sbi, Yu, Yi,
            b1, w2b, b2, w3, b3, out, Bn);
}

// Round 13
// 55.909 us; speedup vs baseline: 2.4408x; 2.4408x over previous
//
#include <hip/hip_runtime.h>
#include <hip/hip_bf16.h>
#include <math.h>

#define KN 20
#define DD 64
#define WPB 4
#define NUSERS 100000
#define NITEMS 50000
#define UG32 3125      // 100000/32 user row-groups (exact)
#define IG32 1563      // ceil(50000/32) item row-groups (tail guarded)
#define TG32 (UG32 + IG32)   // 4688 wave-groups of Y work
#define NBY 1172       // ceil(TG32/4) Y blocks
#define NBS 128        // score-convert blocks (only when ws is big enough)
#define SROW 24        // padded bf16 score row stride (48B, zeros 20..23)

typedef __hip_bfloat16 bf16;
typedef __attribute__((ext_vector_type(8))) short short8;   // 8 bf16 (4 VGPRs)
typedef __attribute__((ext_vector_type(16))) float f32x16;  // MFMA 32x32 acc

__device__ inline ushort f2bf(float f) {                    // fp32 -> bf16 RNE
    unsigned u = __builtin_bit_cast(unsigned, f);
    u += 0x7fffu + ((u >> 16) & 1u);
    return (ushort)(u >> 16);
}
__device__ inline float bf2f(ushort h) {                    // bf16 -> fp32 (exact)
    unsigned u = ((unsigned)h) << 16;
    return __builtin_bit_cast(float, u);
}

// ====== precompute: Y = emb @ W1part via MFMA (register-only); w2 frag table;
//        scores -> bf16 (chunk-parallel) ======================================
// R12 post-mortem: lane=row vector version was cache-thrashing + SMEM-latency
// bound (8.5% VALU, 81MB fetch, 108us). Now: 32-row groups on the matrix pipe.
// A-frag loads E[base+(l&31)][16t+8(l>>5)+j]: one wave-instruction = 32 rows x
// 64B contiguous -> 100% cacheline use, ZERO LDS/DS, no barriers.
// Accuracy: emb split hi/lo bf16 (2 MFMAs) so only w1's single bf16 rounding
// is new vs R12 (Y-storage rounding unchanged) -> absmax ~0.005 expected.
__global__ __launch_bounds__(256, 4) void precompute_Y(
    const float* __restrict__ emb_u, const float* __restrict__ emb_i,
    const float* __restrict__ w1, const float* __restrict__ w2,
    const float* __restrict__ uscr, const float* __restrict__ iscr,
    bf16* __restrict__ Yu, bf16* __restrict__ Yi, ushort* __restrict__ w2b,
    ushort* __restrict__ sbu, ushort* __restrict__ sbi)
{
    const int w    = threadIdx.x >> 6;
    const int lane = threadIdx.x & 63;
    const int g    = lane >> 5;
    const int c    = lane & 31;
    const int bid  = (int)blockIdx.x;

    // ---- score tables -> bf16, chunk-parallel (1 thread = one 16B out chunk) --
    if (bid >= NBY) {
        const int t0 = (bid - NBY) * 256 + (int)threadIdx.x;
        const int NCH = 3 * (NUSERS + NITEMS);
        for (int cch = t0; cch < NCH; cch += NBS * 256) {
            int r = cch / 3, part = cch - 3 * r;
            const float* src = (r < NUSERS) ? (uscr + (size_t)r * KN)
                                            : (iscr + (size_t)(r - NUSERS) * KN);
            ushort* dst = (r < NUSERS) ? (sbu + (size_t)r * SROW)
                                       : (sbi + (size_t)(r - NUSERS) * SROW);
            ushort tmp[8];
            if (part < 2) {
                float4 v0 = *(const float4*)(src + 8 * part);
                float4 v1 = *(const float4*)(src + 8 * part + 4);
                tmp[0] = f2bf(v0.x); tmp[1] = f2bf(v0.y);
                tmp[2] = f2bf(v0.z); tmp[3] = f2bf(v0.w);
                tmp[4] = f2bf(v1.x); tmp[5] = f2bf(v1.y);
                tmp[6] = f2bf(v1.z); tmp[7] = f2bf(v1.w);
            } else {
                float4 v0 = *(const float4*)(src + 16);
                tmp[0] = f2bf(v0.x); tmp[1] = f2bf(v0.y);
                tmp[2] = f2bf(v0.z); tmp[3] = f2bf(v0.w);
                tmp[4] = tmp[5] = tmp[6] = tmp[7] = 0;
            }
            *(short8*)(dst + 8 * part) = *(const short8*)tmp;
        }
        return;
    }

    // ---- w2 -> MFMA-B fragment order (last Y block, all 256 threads) ----
    if (bid == NBY - 1) {
        const int tid = threadIdx.x;
        const int t = tid >> 6, gg = (tid >> 5) & 1, o = tid & 31;
        #pragma unroll
        for (int j = 0; j < 8; ++j)
            w2b[(size_t)tid * 8 + j] = f2bf(w2[(16 * t + 8 * gg + j) * 32 + o]);
    }

    // ---- Y compute: one wave per 32-row group, MFMA, register-only ----
    const int wid = bid * WPB + w;
    if (wid >= TG32) return;
    const bool isU = wid < UG32;
    const float* __restrict__ E  = isU ? emb_u : emb_i;
    ushort* __restrict__      Y  = (ushort*)(isU ? Yu : Yi);
    const float* __restrict__ ws = w1 + (isU ? 0 : 64) * DD;
    const int nrows = isU ? NUSERS : NITEMS;
    const int base  = (isU ? wid : wid - UG32) * 32;

    // B frags: this side's w1 (64x64) -> bf16 frag order, held in 32 VGPRs.
    // B[t][n][j] = w1[16t+8g+j][32n+c]; loads coalesced 128B/instr, L1-hot.
    short8 Bf[4][2];
    #pragma unroll
    for (int t = 0; t < 4; ++t)
        #pragma unroll
        for (int n = 0; n < 2; ++n)
            #pragma unroll
            for (int j = 0; j < 8; ++j)
                Bf[t][n][j] = (short)f2bf(ws[(16 * t + 8 * g + j) * DD + 32 * n + c]);

    int arow = base + c;
    if (arow >= nrows) arow = nrows - 1;   // item tail: dup loads, stores guarded
    const float* __restrict__ er = E + (size_t)arow * DD + 8 * g;

    f32x16 a0 = {};   // Y cols 0..31
    f32x16 a1 = {};   // Y cols 32..63
    #pragma unroll
    for (int t = 0; t < 4; ++t) {
        // one wave-instr = 32 rows x 64B contiguous (g0: +0..31, g1: +32..63)
        float4 v0 = *(const float4*)(er + 16 * t);
        float4 v1 = *(const float4*)(er + 16 * t + 4);
        float f[8] = {v0.x, v0.y, v0.z, v0.w, v1.x, v1.y, v1.z, v1.w};
        short8 Ah, Al;
        #pragma unroll
        for (int j = 0; j < 8; ++j) {
            ushort h = f2bf(f[j]);
            Ah[j] = (short)h;
            Al[j] = (short)f2bf(f[j] - bf2f(h));   // residual: emb near-exact
        }
        a0 = __builtin_amdgcn_mfma_f32_32x32x16_bf16(Ah, Bf[t][0], a0, 0, 0, 0);
        a1 = __builtin_amdgcn_mfma_f32_32x32x16_bf16(Ah, Bf[t][1], a1, 0, 0, 0);
        a0 = __builtin_amdgcn_mfma_f32_32x32x16_bf16(Al, Bf[t][0], a0, 0, 0, 0);
        a1 = __builtin_amdgcn_mfma_f32_32x32x16_bf16(Al, Bf[t][1], a1, 0, 0, 0);
    }

    // C store: row=(r&3)+8*(r>>2)+4g, col=c / 32+c; half-wave rows -> 64B merges
    #pragma unroll
    for (int r = 0; r < 16; ++r) {
        const int grow = base + (r & 3) + 8 * (r >> 2) + 4 * g;
        if (grow < nrows) {
            Y[(size_t)grow * DD + c]      = f2bf(a0[r]);
            Y[(size_t)grow * DD + 32 + c] = f2bf(a1[r]);
        }
    }
}

// ================= main fused kernel (unchanged from R11/R12) =================
// GEMM1 on MFMA (R8/R9 verified layouts); Y rows staged via wave-private LDS;
// B-frags = ds_read_u16 w/ offset immediates; A-frags = direct 16B loads from
// pre-converted bf16 score tables (SBF). h1 (bf16, XOR-swizzled) unions into
// the user staging region; all LDS wave-private -> barrier-free.
template<bool SBF>
__global__ __launch_bounds__(256, 8) void cnn_main(
    const int* __restrict__ user_idxs, const int* __restrict__ item_idxs,
    const int* __restrict__ user_idx_tensor, const float* __restrict__ uscr_f,
    const ushort* __restrict__ uscr_b,
    const int* __restrict__ item_idx_tensor, const float* __restrict__ iscr_f,
    const ushort* __restrict__ iscr_b,
    const bf16* __restrict__ Yu, const bf16* __restrict__ Yi,
    const float* __restrict__ b1, const ushort* __restrict__ w2b,
    const float* __restrict__ b2,
    const float* __restrict__ w3, const float* __restrict__ b3,
    float* __restrict__ out, int Bn)
{
    __shared__ ushort buf[WPB][3072];  // [side][24][64] staging; h1 reuses [0..1280)

    const int w    = threadIdx.x >> 6;
    const int lane = threadIdx.x & 63;
    const int g    = lane >> 5;            // half-wave group (k-octet select)
    const int c    = lane & 31;            // tile column / row index
    const int b = blockIdx.x * WPB + w;
    if (b >= Bn) return;                   // no barriers -> divergence-safe

    const int uid = user_idxs[b];
    const int iid = item_idxs[b];

    int nvu = 0, nvi = 0;
    if (lane < KN) {
        nvu = user_idx_tensor[uid * KN + lane];
        nvi = item_idx_tensor[iid * KN + lane];
    }

    // ---- stage Y rows (both sides) into wave-private LDS, coalesced ----
    #pragma unroll
    for (int side = 0; side < 2; ++side) {
        const ushort* Y = (const ushort*)(side ? Yi : Yu);
        const int nv = side ? nvi : nvu;
        #pragma unroll
        for (int i = 0; i < 3; ++i) {                 // rows 8i..8i+7 (16..23 pad junk)
            int nr = __shfl(nv, 8 * i + (lane >> 3)); // lanes>=KN give nv=0: safe
            short8 v = *(const short8*)(Y + (size_t)nr * DD + (lane & 7) * 8);
            *(short8*)&buf[w][side * 1536 + i * 512 + lane * 8] = v;
        }
    }

    f32x16 acc0 = {};   // h1 cols 0..31
    f32x16 acc1 = {};   // h1 cols 32..63

    #pragma unroll
    for (int side = 0; side < 2; ++side) {
        const int nv = side ? nvi : nvu;
        const int n_r = __shfl(nv, c);

        // ---- A frags: score row (l&31), k-octet 8g+j ----
        short8 A0, A1;
        if (SBF) {
            const ushort* sr = (side ? iscr_b : uscr_b) + (size_t)n_r * SROW;
            A0 = *(const short8*)(sr + 8 * g);     // k 8g..8g+7
            A1 = *(const short8*)(sr + 16);        // k 16..23 (20..23 are zeros)
        } else {
            const float* arow = (side ? iscr_f : uscr_f) + (size_t)n_r * KN;
            float4 a0 = *(const float4*)(arow + 8 * g);
            float4 a1 = *(const float4*)(arow + 8 * g + 4);
            A0[0] = (short)f2bf(a0.x); A0[1] = (short)f2bf(a0.y);
            A0[2] = (short)f2bf(a0.z); A0[3] = (short)f2bf(a0.w);
            A0[4] = (short)f2bf(a1.x); A0[5] = (short)f2bf(a1.y);
            A0[6] = (short)f2bf(a1.z); A0[7] = (short)f2bf(a1.w);
            float4 a2 = *(const float4*)(arow + 16);
            A1 = short8{};
            A1[0] = (short)f2bf(a2.x); A1[1] = (short)f2bf(a2.y);
            A1[2] = (short)f2bf(a2.z); A1[3] = (short)f2bf(a2.w);
        }

        // ---- B frags from LDS (base reg + offset immediates) ----
        const int sb0 = side * 1536;
        short8 B00, B01;
        #pragma unroll
        for (int j = 0; j < 8; ++j) {
            B00[j] = (short)buf[w][sb0 + (8 * g + j) * DD + c];
            B01[j] = (short)buf[w][sb0 + (8 * g + j) * DD + 32 + c];
        }
        acc0 = __builtin_amdgcn_mfma_f32_32x32x16_bf16(A0, B00, acc0, 0, 0, 0);
        acc1 = __builtin_amdgcn_mfma_f32_32x32x16_bf16(A0, B01, acc1, 0, 0, 0);

        short8 B10 = {}, B11 = {};
        if (g == 0) {                                  // rows 16..19; g1 keeps zeros
            #pragma unroll
            for (int j = 0; j < 4; ++j) {
                B10[j] = (short)buf[w][sb0 + (16 + j) * DD + c];
                B11[j] = (short)buf[w][sb0 + (16 + j) * DD + 32 + c];
            }
        }
        acc0 = __builtin_amdgcn_mfma_f32_32x32x16_bf16(A1, B10, acc0, 0, 0, 0);
        acc1 = __builtin_amdgcn_mfma_f32_32x32x16_bf16(A1, B11, acc1, 0, 0, 0);
    }

    // ---- bias + relu -> bf16 -> swizzled LDS rows<20 (reuses [0..1280)) ----
    const float b1v0 = b1[c];
    const float b1v1 = b1[32 + c];
    #pragma unroll
    for (int r = 0; r < 12; ++r) {
        const int row = (r & 3) + 8 * (r >> 2) + 4 * g;
        if (row < KN) {
            const int ch0 = (c >> 3) ^ (row & 7);
            const int ch1 = (4 + (c >> 3)) ^ (row & 7);
            buf[w][row * DD + ch0 * 8 + (c & 7)] = f2bf(fmaxf(acc0[r] + b1v0, 0.f));
            buf[w][row * DD + ch1 * 8 + (c & 7)] = f2bf(fmaxf(acc1[r] + b1v1, 0.f));
        }
    }

    // ---- layer2 MFMA: h2(20x32) = h1(20x64) @ w2(64x32), 4 K-steps ----
    const int ar = (c < KN) ? c : 0;       // clamp A row (rows>=20 don't-care)
    f32x16 c2 = {};
    #pragma unroll
    for (int t = 0; t < 4; ++t) {
        const int chunk = (2 * t + g) ^ (ar & 7);
        short8 A = *(const short8*)&buf[w][ar * DD + chunk * 8];
        short8 B = *(const short8*)&w2b[(size_t)(((t * 2 + g) * 32 + c)) * 8];
        c2 = __builtin_amdgcn_mfma_f32_32x32x16_bf16(A, B, c2, 0, 0, 0);
    }

    // ---- layer3: bias+relu, *w3, butterfly over 32 cols, sigmoid, mean ----
    const float b2v = b2[c];
    const float w3v = w3[c];
    const float b3v = b3[0];
    float sum = 0.f;
    #pragma unroll
    for (int r = 0; r < 12; ++r) {
        float h2v = fmaxf(c2[r] + b2v, 0.f);
        float p = h2v * w3v;
        #pragma unroll
        for (int off = 16; off > 0; off >>= 1)
            p += __shfl_xor(p, off);               // sum over 32 out-cols
        float logit = p + b3v;
        if (g == 0 || r < 8)                       // valid rows: g0 12, g1 8 (=20)
            sum += 1.f / (1.f + __expf(-logit));
    }
    sum += __shfl_xor(sum, 32);
    if (lane == 0) out[b] = sum * (1.f / KN);
}

extern "C" void kernel_launch(void* const* d_in, const int* in_sizes, int n_in,
                              void* d_out, int out_size, void* d_ws, size_t ws_size,
                              hipStream_t stream) {
    const int*   user_idxs       = (const int*)  d_in[0];
    const int*   item_idxs       = (const int*)  d_in[1];
    const int*   user_idx_tensor = (const int*)  d_in[2];
    const float* user_scr_tensor = (const float*)d_in[3];
    const int*   item_idx_tensor = (const int*)  d_in[4];
    const float* item_scr_tensor = (const float*)d_in[5];
    const float* user_emb        = (const float*)d_in[6];
    const float* item_emb        = (const float*)d_in[7];
    const float* w1 = (const float*)d_in[8];
    const float* b1 = (const float*)d_in[9];
    const float* w2 = (const float*)d_in[10];
    const float* b2 = (const float*)d_in[11];
    const float* w3 = (const float*)d_in[12];
    const float* b3 = (const float*)d_in[13];
    float* out = (float*)d_out;

    const int Bn = in_sizes[0];

    // ws: Yu bf16[100000*64] | Yi bf16[50000*64] | w2b u16[2048] | sbu | sbi
    bf16*   Yu  = (bf16*)d_ws;
    bf16*   Yi  = Yu + (size_t)NUSERS * DD;
    ushort* w2b = (ushort*)(Yi + (size_t)NITEMS * DD);
    ushort* sbu = w2b + 2048;
    ushort* sbi = sbu + (size_t)NUSERS * SROW;

    const size_t need = (size_t)(NUSERS + NITEMS) * DD * 2 + 2048 * 2
                      + (size_t)(NUSERS + NITEMS) * SROW * 2;
    const bool big = ws_size >= need;

    precompute_Y<<<NBY + (big ? NBS : 0), 256, 0, stream>>>(
        user_emb, item_emb, w1, w2, user_scr_tensor, item_scr_tensor,
        Yu, Yi, w2b, sbu, sbi);

    const int grid = (Bn + WPB - 1) / WPB;
    if (big)
        cnn_main<true><<<grid, 256, 0, stream>>>(
            user_idxs, item_idxs, user_idx_tensor, user_scr_tensor, sbu,
            item_idx_tensor, item_scr_tensor, sbi, Yu, Yi,
            b1, w2b, b2, w3, b3, out, Bn);
    else
        cnn_main<false><<<grid, 256, 0, stream>>>(
            user_idxs, item_idxs, user_idx_tensor, user_scr_tensor, sbu,
            item_idx_tensor, item_scr_tensor, sbi, Yu, Yi,
            b1, w2b, b2, w3, b3, out, Bn);
}

// Round 14
// 53.146 us; speedup vs baseline: 2.5677x; 1.0520x over previous
//
#include <hip/hip_runtime.h>
#include <hip/hip_bf16.h>
#include <math.h>

#define KN 20
#define DD 64
#define WPB 4
#define NUSERS 100000
#define NITEMS 50000
#define UG32 3125      // 100000/32 user row-groups (exact)
#define IG32 1563      // ceil(50000/32) item row-groups (tail guarded)
#define TG32 (UG32 + IG32)   // 4688 wave-groups of Y work
#define NBY 1172       // ceil(TG32/4) Y blocks
#define NBS 256        // score-convert blocks, dispatched FIRST (overlap w/ Y)
#define SROW 24        // padded bf16 score row stride (48B, zeros 20..23)

typedef __hip_bfloat16 bf16;
typedef __attribute__((ext_vector_type(8))) short short8;   // 8 bf16 (4 VGPRs)
typedef __attribute__((ext_vector_type(16))) float f32x16;  // MFMA 32x32 acc

__device__ inline ushort f2bf(float f) {                    // fp32 -> bf16 RNE
    unsigned u = __builtin_bit_cast(unsigned, f);
    u += 0x7fffu + ((u >> 16) & 1u);
    return (ushort)(u >> 16);
}
__device__ inline float bf2f(ushort h) {                    // bf16 -> fp32 (exact)
    unsigned u = ((unsigned)h) << 16;
    return __builtin_bit_cast(float, u);
}

// ====== precompute: scores->bf16 (FIRST blocks); Y = emb @ W1part via MFMA ====
// Convert blocks dispatched first so they overlap Y blocks instead of running
// as an under-occupied tail (R13: converts were the last 128 blocks).
__global__ __launch_bounds__(256, 4) void precompute_Y(
    const float* __restrict__ emb_u, const float* __restrict__ emb_i,
    const float* __restrict__ w1, const float* __restrict__ w2,
    const float* __restrict__ uscr, const float* __restrict__ iscr,
    bf16* __restrict__ Yu, bf16* __restrict__ Yi, ushort* __restrict__ w2b,
    ushort* __restrict__ sbu, ushort* __restrict__ sbi, int convblks)
{
    const int w    = threadIdx.x >> 6;
    const int lane = threadIdx.x & 63;
    const int g    = lane >> 5;
    const int c    = lane & 31;
    const int bid  = (int)blockIdx.x;

    // ---- score tables -> bf16, chunk-parallel (1 thread = one 16B out chunk) --
    if (bid < convblks) {
        const int t0 = bid * 256 + (int)threadIdx.x;
        const int NCH = 3 * (NUSERS + NITEMS);
        for (int cch = t0; cch < NCH; cch += convblks * 256) {
            int r = cch / 3, part = cch - 3 * r;
            const float* src = (r < NUSERS) ? (uscr + (size_t)r * KN)
                                            : (iscr + (size_t)(r - NUSERS) * KN);
            ushort* dst = (r < NUSERS) ? (sbu + (size_t)r * SROW)
                                       : (sbi + (size_t)(r - NUSERS) * SROW);
            ushort tmp[8];
            if (part < 2) {
                float4 v0 = *(const float4*)(src + 8 * part);
                float4 v1 = *(const float4*)(src + 8 * part + 4);
                tmp[0] = f2bf(v0.x); tmp[1] = f2bf(v0.y);
                tmp[2] = f2bf(v0.z); tmp[3] = f2bf(v0.w);
                tmp[4] = f2bf(v1.x); tmp[5] = f2bf(v1.y);
                tmp[6] = f2bf(v1.z); tmp[7] = f2bf(v1.w);
            } else {
                float4 v0 = *(const float4*)(src + 16);
                tmp[0] = f2bf(v0.x); tmp[1] = f2bf(v0.y);
                tmp[2] = f2bf(v0.z); tmp[3] = f2bf(v0.w);
                tmp[4] = tmp[5] = tmp[6] = tmp[7] = 0;
            }
            *(short8*)(dst + 8 * part) = *(const short8*)tmp;
        }
        return;
    }

    const int yid = bid - convblks;

    // ---- w2 -> MFMA-B fragment order (first Y block; always present) ----
    if (yid == 0) {
        const int tid = threadIdx.x;
        const int t = tid >> 6, gg = (tid >> 5) & 1, o = tid & 31;
        #pragma unroll
        for (int j = 0; j < 8; ++j)
            w2b[(size_t)tid * 8 + j] = f2bf(w2[(16 * t + 8 * gg + j) * 32 + o]);
    }

    // ---- Y compute: one wave per 32-row group, MFMA, register-only (R13) ----
    const int wid = yid * WPB + w;
    if (wid >= TG32) return;
    const bool isU = wid < UG32;
    const float* __restrict__ E  = isU ? emb_u : emb_i;
    ushort* __restrict__      Y  = (ushort*)(isU ? Yu : Yi);
    const float* __restrict__ ws = w1 + (isU ? 0 : 64) * DD;
    const int nrows = isU ? NUSERS : NITEMS;
    const int base  = (isU ? wid : wid - UG32) * 32;

    short8 Bf[4][2];
    #pragma unroll
    for (int t = 0; t < 4; ++t)
        #pragma unroll
        for (int n = 0; n < 2; ++n)
            #pragma unroll
            for (int j = 0; j < 8; ++j)
                Bf[t][n][j] = (short)f2bf(ws[(16 * t + 8 * g + j) * DD + 32 * n + c]);

    int arow = base + c;
    if (arow >= nrows) arow = nrows - 1;   // item tail: dup loads, stores guarded
    const float* __restrict__ er = E + (size_t)arow * DD + 8 * g;

    f32x16 a0 = {};   // Y cols 0..31
    f32x16 a1 = {};   // Y cols 32..63
    #pragma unroll
    for (int t = 0; t < 4; ++t) {
        float4 v0 = *(const float4*)(er + 16 * t);
        float4 v1 = *(const float4*)(er + 16 * t + 4);
        float f[8] = {v0.x, v0.y, v0.z, v0.w, v1.x, v1.y, v1.z, v1.w};
        short8 Ah, Al;
        #pragma unroll
        for (int j = 0; j < 8; ++j) {
            ushort h = f2bf(f[j]);
            Ah[j] = (short)h;
            Al[j] = (short)f2bf(f[j] - bf2f(h));   // residual: emb near-exact
        }
        a0 = __builtin_amdgcn_mfma_f32_32x32x16_bf16(Ah, Bf[t][0], a0, 0, 0, 0);
        a1 = __builtin_amdgcn_mfma_f32_32x32x16_bf16(Ah, Bf[t][1], a1, 0, 0, 0);
        a0 = __builtin_amdgcn_mfma_f32_32x32x16_bf16(Al, Bf[t][0], a0, 0, 0, 0);
        a1 = __builtin_amdgcn_mfma_f32_32x32x16_bf16(Al, Bf[t][1], a1, 0, 0, 0);
    }

    #pragma unroll
    for (int r = 0; r < 16; ++r) {
        const int grow = base + (r & 3) + 8 * (r >> 2) + 4 * g;
        if (grow < nrows) {
            Y[(size_t)grow * DD + c]      = f2bf(a0[r]);
            Y[(size_t)grow * DD + 32 + c] = f2bf(a1[r]);
        }
    }
}

// ================= main fused kernel ==========================================
// R13 structure; NEW: B-frags via paired-dword LDS reads (merge to ds_read2_b32)
// + v_perm column pack -- cnn_main was DS-pipe bound (~82 DS ops/wave, 48 of
// them unmergeable ds_read_u16 at 128B stride). Same values, bit-identical.
template<bool SBF>
__global__ __launch_bounds__(256, 8) void cnn_main(
    const int* __restrict__ user_idxs, const int* __restrict__ item_idxs,
    const int* __restrict__ user_idx_tensor, const float* __restrict__ uscr_f,
    const ushort* __restrict__ uscr_b,
    const int* __restrict__ item_idx_tensor, const float* __restrict__ iscr_f,
    const ushort* __restrict__ iscr_b,
    const bf16* __restrict__ Yu, const bf16* __restrict__ Yi,
    const float* __restrict__ b1, const ushort* __restrict__ w2b,
    const float* __restrict__ b2,
    const float* __restrict__ w3, const float* __restrict__ b3,
    float* __restrict__ out, int Bn)
{
    __shared__ ushort buf[WPB][3072];  // [side][24][64] staging; h1 reuses [0..1280)

    const int w    = threadIdx.x >> 6;
    const int lane = threadIdx.x & 63;
    const int g    = lane >> 5;            // half-wave group (k-octet select)
    const int c    = lane & 31;            // tile column / row index
    const int b = blockIdx.x * WPB + w;
    if (b >= Bn) return;                   // no barriers -> divergence-safe

    const int uid = user_idxs[b];
    const int iid = item_idxs[b];

    int nvu = 0, nvi = 0;
    if (lane < KN) {
        nvu = user_idx_tensor[uid * KN + lane];
        nvi = item_idx_tensor[iid * KN + lane];
    }

    // ---- stage Y rows (both sides) into wave-private LDS, coalesced ----
    #pragma unroll
    for (int side = 0; side < 2; ++side) {
        const ushort* Y = (const ushort*)(side ? Yi : Yu);
        const int nv = side ? nvi : nvu;
        #pragma unroll
        for (int i = 0; i < 3; ++i) {                 // rows 8i..8i+7 (16..23 pad junk)
            int nr = __shfl(nv, 8 * i + (lane >> 3)); // lanes>=KN give nv=0: safe
            short8 v = *(const short8*)(Y + (size_t)nr * DD + (lane & 7) * 8);
            *(short8*)&buf[w][side * 1536 + i * 512 + lane * 8] = v;
        }
    }

    f32x16 acc0 = {};   // h1 cols 0..31
    f32x16 acc1 = {};   // h1 cols 32..63

    // v_perm selector: pack col c from two row-dwords (each dword = cols 2m,2m+1)
    const uint selp = 0x05040100u | ((c & 1) ? 0x02020202u : 0x0u);
    const int  cb   = c & ~1;              // even ushort col of the dword pair

    #pragma unroll
    for (int side = 0; side < 2; ++side) {
        const int nv = side ? nvi : nvu;
        const int n_r = __shfl(nv, c);

        // ---- A frags: score row (l&31), k-octet 8g+j ----
        short8 A0, A1;
        if (SBF) {
            const ushort* sr = (side ? iscr_b : uscr_b) + (size_t)n_r * SROW;
            A0 = *(const short8*)(sr + 8 * g);     // k 8g..8g+7
            A1 = *(const short8*)(sr + 16);        // k 16..23 (20..23 are zeros)
        } else {
            const float* arow = (side ? iscr_f : uscr_f) + (size_t)n_r * KN;
            float4 a0 = *(const float4*)(arow + 8 * g);
            float4 a1 = *(const float4*)(arow + 8 * g + 4);
            A0[0] = (short)f2bf(a0.x); A0[1] = (short)f2bf(a0.y);
            A0[2] = (short)f2bf(a0.z); A0[3] = (short)f2bf(a0.w);
            A0[4] = (short)f2bf(a1.x); A0[5] = (short)f2bf(a1.y);
            A0[6] = (short)f2bf(a1.z); A0[7] = (short)f2bf(a1.w);
            float4 a2 = *(const float4*)(arow + 16);
            A1 = short8{};
            A1[0] = (short)f2bf(a2.x); A1[1] = (short)f2bf(a2.y);
            A1[2] = (short)f2bf(a2.z); A1[3] = (short)f2bf(a2.w);
        }

        // ---- B frags: dword reads (rows merge to ds_read2_b32) + v_perm ----
        const int sb0u = side * 1536;
        uint r0[8], r1[8];                 // row dwords for cols (cb,cb+1)/(32+cb,+1)
        #pragma unroll
        for (int j = 0; j < 8; ++j) {
            r0[j] = *(const uint*)&buf[w][sb0u + (8 * g + j) * DD + cb];
            r1[j] = *(const uint*)&buf[w][sb0u + (8 * g + j) * DD + 32 + cb];
        }
        uint4 pk0, pk1;
        pk0.x = __builtin_amdgcn_perm(r0[1], r0[0], selp);
        pk0.y = __builtin_amdgcn_perm(r0[3], r0[2], selp);
        pk0.z = __builtin_amdgcn_perm(r0[5], r0[4], selp);
        pk0.w = __builtin_amdgcn_perm(r0[7], r0[6], selp);
        pk1.x = __builtin_amdgcn_perm(r1[1], r1[0], selp);
        pk1.y = __builtin_amdgcn_perm(r1[3], r1[2], selp);
        pk1.z = __builtin_amdgcn_perm(r1[5], r1[4], selp);
        pk1.w = __builtin_amdgcn_perm(r1[7], r1[6], selp);
        short8 B00 = __builtin_bit_cast(short8, pk0);
        short8 B01 = __builtin_bit_cast(short8, pk1);
        acc0 = __builtin_amdgcn_mfma_f32_32x32x16_bf16(A0, B00, acc0, 0, 0, 0);
        acc1 = __builtin_amdgcn_mfma_f32_32x32x16_bf16(A0, B01, acc1, 0, 0, 0);

        // kstep1: rows 16..19 for g0; zeros for g1 (read unconditionally, mask)
        uint q0[4], q1[4];
        #pragma unroll
        for (int j = 0; j < 4; ++j) {
            q0[j] = *(const uint*)&buf[w][sb0u + (16 + j) * DD + cb];
            q1[j] = *(const uint*)&buf[w][sb0u + (16 + j) * DD + 32 + cb];
        }
        uint4 pk2 = {}, pk3 = {};
        if (g == 0) {
            pk2.x = __builtin_amdgcn_perm(q0[1], q0[0], selp);
            pk2.y = __builtin_amdgcn_perm(q0[3], q0[2], selp);
            pk3.x = __builtin_amdgcn_perm(q1[1], q1[0], selp);
            pk3.y = __builtin_amdgcn_perm(q1[3], q1[2], selp);
        }
        short8 B10 = __builtin_bit_cast(short8, pk2);
        short8 B11 = __builtin_bit_cast(short8, pk3);
        acc0 = __builtin_amdgcn_mfma_f32_32x32x16_bf16(A1, B10, acc0, 0, 0, 0);
        acc1 = __builtin_amdgcn_mfma_f32_32x32x16_bf16(A1, B11, acc1, 0, 0, 0);
    }

    // ---- bias + relu -> bf16 -> swizzled LDS rows<20 (reuses [0..1280)) ----
    const float b1v0 = b1[c];
    const float b1v1 = b1[32 + c];
    #pragma unroll
    for (int r = 0; r < 12; ++r) {
        const int row = (r & 3) + 8 * (r >> 2) + 4 * g;
        if (row < KN) {
            const int ch0 = (c >> 3) ^ (row & 7);
            const int ch1 = (4 + (c >> 3)) ^ (row & 7);
            buf[w][row * DD + ch0 * 8 + (c & 7)] = f2bf(fmaxf(acc0[r] + b1v0, 0.f));
            buf[w][row * DD + ch1 * 8 + (c & 7)] = f2bf(fmaxf(acc1[r] + b1v1, 0.f));
        }
    }

    // ---- layer2 MFMA: h2(20x32) = h1(20x64) @ w2(64x32), 4 K-steps ----
    const int ar = (c < KN) ? c : 0;       // clamp A row (rows>=20 don't-care)
    f32x16 c2 = {};
    #pragma unroll
    for (int t = 0; t < 4; ++t) {
        const int chunk = (2 * t + g) ^ (ar & 7);
        short8 A = *(const short8*)&buf[w][ar * DD + chunk * 8];
        short8 B = *(const short8*)&w2b[(size_t)(((t * 2 + g) * 32 + c)) * 8];
        c2 = __builtin_amdgcn_mfma_f32_32x32x16_bf16(A, B, c2, 0, 0, 0);
    }

    // ---- layer3: bias+relu, *w3, butterfly over 32 cols, sigmoid, mean ----
    const float b2v = b2[c];
    const float w3v = w3[c];
    const float b3v = b3[0];
    float sum = 0.f;
    #pragma unroll
    for (int r = 0; r < 12; ++r) {
        float h2v = fmaxf(c2[r] + b2v, 0.f);
        float p = h2v * w3v;
        #pragma unroll
        for (int off = 16; off > 0; off >>= 1)
            p += __shfl_xor(p, off);               // sum over 32 out-cols
        float logit = p + b3v;
        if (g == 0 || r < 8)                       // valid rows: g0 12, g1 8 (=20)
            sum += 1.f / (1.f + __expf(-logit));
    }
    sum += __shfl_xor(sum, 32);
    if (lane == 0) out[b] = sum * (1.f / KN);
}

extern "C" void kernel_launch(void* const* d_in, const int* in_sizes, int n_in,
                              void* d_out, int out_size, void* d_ws, size_t ws_size,
                              hipStream_t stream) {
    const int*   user_idxs       = (const int*)  d_in[0];
    const int*   item_idxs       = (const int*)  d_in[1];
    const int*   user_idx_tensor = (const int*)  d_in[2];
    const float* user_scr_tensor = (const float*)d_in[3];
    const int*   item_idx_tensor = (const int*)  d_in[4];
    const float* item_scr_tensor = (const float*)d_in[5];
    const float* user_emb        = (const float*)d_in[6];
    const float* item_emb        = (const float*)d_in[7];
    const float* w1 = (const float*)d_in[8];
    const float* b1 = (const float*)d_in[9];
    const float* w2 = (const float*)d_in[10];
    const float* b2 = (const float*)d_in[11];
    const float* w3 = (const float*)d_in[12];
    const float* b3 = (const float*)d_in[13];
    float* out = (float*)d_out;

    const int Bn = in_sizes[0];

    // ws: Yu bf16[100000*64] | Yi bf16[50000*64] | w2b u16[2048] | sbu | sbi
    bf16*   Yu  = (bf16*)d_ws;
    bf16*   Yi  = Yu + (size_t)NUSERS * DD;
    ushort* w2b = (ushort*)(Yi + (size_t)NITEMS * DD);
    ushort* sbu = w2b + 2048;
    ushort* sbi = sbu + (size_t)NUSERS * SROW;

    const size_t need = (size_t)(NUSERS + NITEMS) * DD * 2 + 2048 * 2
                      + (size_t)(NUSERS + NITEMS) * SROW * 2;
    const bool big = ws_size >= need;
    const int convblks = big ? NBS : 0;

    precompute_Y<<<convblks + NBY, 256, 0, stream>>>(
        user_emb, item_emb, w1, w2, user_scr_tensor, item_scr_tensor,
        Yu, Yi, w2b, sbu, sbi, convblks);

    const int grid = (Bn + WPB - 1) / WPB;
    if (big)
        cnn_main<true><<<grid, 256, 0, stream>>>(
            user_idxs, item_idxs, user_idx_tensor, user_scr_tensor, sbu,
            item_idx_tensor, item_scr_tensor, sbi, Yu, Yi,
            b1, w2b, b2, w3, b3, out, Bn);
    else
        cnn_main<false><<<grid, 256, 0, stream>>>(
            user_idxs, item_idxs, user_idx_tensor, user_scr_tensor, sbu,
            item_idx_tensor, item_scr_tensor, sbi, Yu, Yi,
            b1, w2b, b2, w3, b3, out, Bn);
}

// Round 15
// 52.655 us; speedup vs baseline: 2.5917x; 1.0093x over previous
//
#include <hip/hip_runtime.h>
#include <hip/hip_bf16.h>
#include <math.h>

#define KN 20
#define DD 64
#define WPB 4
#define NUSERS 100000
#define NITEMS 50000
#define UG32 3125      // 100000/32 user row-groups (exact)
#define IG32 1563      // ceil(50000/32) item row-groups (tail guarded)
#define TG32 (UG32 + IG32)   // 4688 wave-groups of Y work
#define NBY 1172       // ceil(TG32/4) Y blocks (convert folded into these)
#define SROW 24        // padded bf16 score row stride (48B, zeros 20..23)

typedef __hip_bfloat16 bf16;
typedef __attribute__((ext_vector_type(8))) short short8;   // 8 bf16 (4 VGPRs)
typedef __attribute__((ext_vector_type(16))) float f32x16;  // MFMA 32x32 acc

__device__ inline ushort f2bf(float f) {                    // fp32 -> bf16 RNE
    unsigned u = __builtin_bit_cast(unsigned, f);
    u += 0x7fffu + ((u >> 16) & 1u);
    return (ushort)(u >> 16);
}
__device__ inline float bf2f(ushort h) {                    // bf16 -> fp32 (exact)
    unsigned u = ((unsigned)h) << 16;
    return __builtin_bit_cast(float, u);
}

// DPP-based 32-lane sum (VALU pipe, zero DS ops). Valid in lanes 31 and 63.
__device__ inline float dpp_sum32(float x) {
    int v = __builtin_bit_cast(int, x);
    float s = x;
    s += __builtin_bit_cast(float, __builtin_amdgcn_update_dpp(0, v, 0x111, 0xf, 0xf, true)); // row_shr:1
    v = __builtin_bit_cast(int, s);
    s += __builtin_bit_cast(float, __builtin_amdgcn_update_dpp(0, v, 0x112, 0xf, 0xf, true)); // row_shr:2
    v = __builtin_bit_cast(int, s);
    s += __builtin_bit_cast(float, __builtin_amdgcn_update_dpp(0, v, 0x114, 0xf, 0xf, true)); // row_shr:4
    v = __builtin_bit_cast(int, s);
    s += __builtin_bit_cast(float, __builtin_amdgcn_update_dpp(0, v, 0x118, 0xf, 0xf, true)); // row_shr:8
    v = __builtin_bit_cast(int, s);
    s += __builtin_bit_cast(float, __builtin_amdgcn_update_dpp(0, v, 0x142, 0xf, 0xf, true)); // ROW_BCAST15
    return s;   // lane15+: partials; lane31 = sum(0..31), lane63 = sum(32..63)
}

// ====== precompute: Y = emb @ W1part via MFMA; w2 frag table; scores->bf16
//        (convert FOLDED into Y blocks -- no dedicated phase) ================
__global__ __launch_bounds__(256, 4) void precompute_Y(
    const float* __restrict__ emb_u, const float* __restrict__ emb_i,
    const float* __restrict__ w1, const float* __restrict__ w2,
    const float* __restrict__ uscr, const float* __restrict__ iscr,
    bf16* __restrict__ Yu, bf16* __restrict__ Yi, ushort* __restrict__ w2b,
    ushort* __restrict__ sbu, ushort* __restrict__ sbi, int dosb)
{
    const int w    = threadIdx.x >> 6;
    const int lane = threadIdx.x & 63;
    const int g    = lane >> 5;
    const int c    = lane & 31;
    const int yid  = (int)blockIdx.x;

    // ---- w2 -> MFMA-B fragment order (first Y block) ----
    if (yid == 0) {
        const int tid = threadIdx.x;
        const int t = tid >> 6, gg = (tid >> 5) & 1, o = tid & 31;
        #pragma unroll
        for (int j = 0; j < 8; ++j)
            w2b[(size_t)tid * 8 + j] = f2bf(w2[(16 * t + 8 * gg + j) * 32 + o]);
    }

    // ---- Y compute: one wave per 32-row group, MFMA, register-only ----
    const int wid = yid * WPB + w;
    if (wid < TG32) {
        const bool isU = wid < UG32;
        const float* __restrict__ E  = isU ? emb_u : emb_i;
        ushort* __restrict__      Y  = (ushort*)(isU ? Yu : Yi);
        const float* __restrict__ ws = w1 + (isU ? 0 : 64) * DD;
        const int nrows = isU ? NUSERS : NITEMS;
        const int base  = (isU ? wid : wid - UG32) * 32;

        short8 Bf[4][2];
        #pragma unroll
        for (int t = 0; t < 4; ++t)
            #pragma unroll
            for (int n = 0; n < 2; ++n)
                #pragma unroll
                for (int j = 0; j < 8; ++j)
                    Bf[t][n][j] = (short)f2bf(ws[(16 * t + 8 * g + j) * DD + 32 * n + c]);

        int arow = base + c;
        if (arow >= nrows) arow = nrows - 1;   // item tail: dup loads, stores guarded
        const float* __restrict__ er = E + (size_t)arow * DD + 8 * g;

        f32x16 a0 = {};   // Y cols 0..31
        f32x16 a1 = {};   // Y cols 32..63
        #pragma unroll
        for (int t = 0; t < 4; ++t) {
            float4 v0 = *(const float4*)(er + 16 * t);
            float4 v1 = *(const float4*)(er + 16 * t + 4);
            float f[8] = {v0.x, v0.y, v0.z, v0.w, v1.x, v1.y, v1.z, v1.w};
            short8 Ah, Al;
            #pragma unroll
            for (int j = 0; j < 8; ++j) {
                ushort h = f2bf(f[j]);
                Ah[j] = (short)h;
                Al[j] = (short)f2bf(f[j] - bf2f(h));   // residual: emb near-exact
            }
            a0 = __builtin_amdgcn_mfma_f32_32x32x16_bf16(Ah, Bf[t][0], a0, 0, 0, 0);
            a1 = __builtin_amdgcn_mfma_f32_32x32x16_bf16(Ah, Bf[t][1], a1, 0, 0, 0);
            a0 = __builtin_amdgcn_mfma_f32_32x32x16_bf16(Al, Bf[t][0], a0, 0, 0, 0);
            a1 = __builtin_amdgcn_mfma_f32_32x32x16_bf16(Al, Bf[t][1], a1, 0, 0, 0);
        }

        #pragma unroll
        for (int r = 0; r < 16; ++r) {
            const int grow = base + (r & 3) + 8 * (r >> 2) + 4 * g;
            if (grow < nrows) {
                Y[(size_t)grow * DD + c]      = f2bf(a0[r]);
                Y[(size_t)grow * DD + 32 + c] = f2bf(a1[r]);
            }
        }
    }

    // ---- score tables -> bf16, folded: this block's grid-stride chunk slice --
    if (dosb) {
        const int t0 = yid * 256 + (int)threadIdx.x;
        const int NCH = 3 * (NUSERS + NITEMS);
        for (int cch = t0; cch < NCH; cch += NBY * 256) {
            int r = cch / 3, part = cch - 3 * r;
            const float* src = (r < NUSERS) ? (uscr + (size_t)r * KN)
                                            : (iscr + (size_t)(r - NUSERS) * KN);
            ushort* dst = (r < NUSERS) ? (sbu + (size_t)r * SROW)
                                       : (sbi + (size_t)(r - NUSERS) * SROW);
            ushort tmp[8];
            if (part < 2) {
                float4 v0 = *(const float4*)(src + 8 * part);
                float4 v1 = *(const float4*)(src + 8 * part + 4);
                tmp[0] = f2bf(v0.x); tmp[1] = f2bf(v0.y);
                tmp[2] = f2bf(v0.z); tmp[3] = f2bf(v0.w);
                tmp[4] = f2bf(v1.x); tmp[5] = f2bf(v1.y);
                tmp[6] = f2bf(v1.z); tmp[7] = f2bf(v1.w);
            } else {
                float4 v0 = *(const float4*)(src + 16);
                tmp[0] = f2bf(v0.x); tmp[1] = f2bf(v0.y);
                tmp[2] = f2bf(v0.z); tmp[3] = f2bf(v0.w);
                tmp[4] = tmp[5] = tmp[6] = tmp[7] = 0;
            }
            *(short8*)(dst + 8 * part) = *(const short8*)tmp;
        }
    }
}

// ================= main fused kernel ==========================================
// R14 structure; NEW: layer3 reduction via DPP (v_add row_shr chain, VALU pipe)
// -- the shfl_xor butterfly was 60 ds_swizzle/wave on the contended DS pipe,
// and only lanes 31/63 carry used results anyway.
template<bool SBF>
__global__ __launch_bounds__(256, 8) void cnn_main(
    const int* __restrict__ user_idxs, const int* __restrict__ item_idxs,
    const int* __restrict__ user_idx_tensor, const float* __restrict__ uscr_f,
    const ushort* __restrict__ uscr_b,
    const int* __restrict__ item_idx_tensor, const float* __restrict__ iscr_f,
    const ushort* __restrict__ iscr_b,
    const bf16* __restrict__ Yu, const bf16* __restrict__ Yi,
    const float* __restrict__ b1, const ushort* __restrict__ w2b,
    const float* __restrict__ b2,
    const float* __restrict__ w3, const float* __restrict__ b3,
    float* __restrict__ out, int Bn)
{
    __shared__ ushort buf[WPB][3072];  // [side][24][64] staging; h1 reuses [0..1280)

    const int w    = threadIdx.x >> 6;
    const int lane = threadIdx.x & 63;
    const int g    = lane >> 5;            // half-wave group (k-octet select)
    const int c    = lane & 31;            // tile column / row index
    const int b = blockIdx.x * WPB + w;
    if (b >= Bn) return;                   // no barriers -> divergence-safe

    const int uid = user_idxs[b];
    const int iid = item_idxs[b];

    int nvu = 0, nvi = 0;
    if (lane < KN) {
        nvu = user_idx_tensor[uid * KN + lane];
        nvi = item_idx_tensor[iid * KN + lane];
    }

    // ---- stage Y rows (both sides) into wave-private LDS, coalesced ----
    #pragma unroll
    for (int side = 0; side < 2; ++side) {
        const ushort* Y = (const ushort*)(side ? Yi : Yu);
        const int nv = side ? nvi : nvu;
        #pragma unroll
        for (int i = 0; i < 3; ++i) {                 // rows 8i..8i+7 (16..23 pad junk)
            int nr = __shfl(nv, 8 * i + (lane >> 3)); // lanes>=KN give nv=0: safe
            short8 v = *(const short8*)(Y + (size_t)nr * DD + (lane & 7) * 8);
            *(short8*)&buf[w][side * 1536 + i * 512 + lane * 8] = v;
        }
    }

    f32x16 acc0 = {};   // h1 cols 0..31
    f32x16 acc1 = {};   // h1 cols 32..63

    // v_perm selector: pack col c from two row-dwords (each dword = cols 2m,2m+1)
    const uint selp = 0x05040100u | ((c & 1) ? 0x02020202u : 0x0u);
    const int  cb   = c & ~1;              // even ushort col of the dword pair

    #pragma unroll
    for (int side = 0; side < 2; ++side) {
        const int nv = side ? nvi : nvu;
        const int n_r = __shfl(nv, c);

        // ---- A frags: score row (l&31), k-octet 8g+j ----
        short8 A0, A1;
        if (SBF) {
            const ushort* sr = (side ? iscr_b : uscr_b) + (size_t)n_r * SROW;
            A0 = *(const short8*)(sr + 8 * g);     // k 8g..8g+7
            A1 = *(const short8*)(sr + 16);        // k 16..23 (20..23 are zeros)
        } else {
            const float* arow = (side ? iscr_f : uscr_f) + (size_t)n_r * KN;
            float4 a0 = *(const float4*)(arow + 8 * g);
            float4 a1 = *(const float4*)(arow + 8 * g + 4);
            A0[0] = (short)f2bf(a0.x); A0[1] = (short)f2bf(a0.y);
            A0[2] = (short)f2bf(a0.z); A0[3] = (short)f2bf(a0.w);
            A0[4] = (short)f2bf(a1.x); A0[5] = (short)f2bf(a1.y);
            A0[6] = (short)f2bf(a1.z); A0[7] = (short)f2bf(a1.w);
            float4 a2 = *(const float4*)(arow + 16);
            A1 = short8{};
            A1[0] = (short)f2bf(a2.x); A1[1] = (short)f2bf(a2.y);
            A1[2] = (short)f2bf(a2.z); A1[3] = (short)f2bf(a2.w);
        }

        // ---- B frags: dword reads (rows merge to ds_read2_b32) + v_perm ----
        const int sb0u = side * 1536;
        uint r0[8], r1[8];                 // row dwords for cols (cb,cb+1)/(32+cb,+1)
        #pragma unroll
        for (int j = 0; j < 8; ++j) {
            r0[j] = *(const uint*)&buf[w][sb0u + (8 * g + j) * DD + cb];
            r1[j] = *(const uint*)&buf[w][sb0u + (8 * g + j) * DD + 32 + cb];
        }
        uint4 pk0, pk1;
        pk0.x = __builtin_amdgcn_perm(r0[1], r0[0], selp);
        pk0.y = __builtin_amdgcn_perm(r0[3], r0[2], selp);
        pk0.z = __builtin_amdgcn_perm(r0[5], r0[4], selp);
        pk0.w = __builtin_amdgcn_perm(r0[7], r0[6], selp);
        pk1.x = __builtin_amdgcn_perm(r1[1], r1[0], selp);
        pk1.y = __builtin_amdgcn_perm(r1[3], r1[2], selp);
        pk1.z = __builtin_amdgcn_perm(r1[5], r1[4], selp);
        pk1.w = __builtin_amdgcn_perm(r1[7], r1[6], selp);
        short8 B00 = __builtin_bit_cast(short8, pk0);
        short8 B01 = __builtin_bit_cast(short8, pk1);
        acc0 = __builtin_amdgcn_mfma_f32_32x32x16_bf16(A0, B00, acc0, 0, 0, 0);
        acc1 = __builtin_amdgcn_mfma_f32_32x32x16_bf16(A0, B01, acc1, 0, 0, 0);

        // kstep1: rows 16..19 for g0; zeros for g1 (read unconditionally, mask)
        uint q0[4], q1[4];
        #pragma unroll
        for (int j = 0; j < 4; ++j) {
            q0[j] = *(const uint*)&buf[w][sb0u + (16 + j) * DD + cb];
            q1[j] = *(const uint*)&buf[w][sb0u + (16 + j) * DD + 32 + cb];
        }
        uint4 pk2 = {}, pk3 = {};
        if (g == 0) {
            pk2.x = __builtin_amdgcn_perm(q0[1], q0[0], selp);
            pk2.y = __builtin_amdgcn_perm(q0[3], q0[2], selp);
            pk3.x = __builtin_amdgcn_perm(q1[1], q1[0], selp);
            pk3.y = __builtin_amdgcn_perm(q1[3], q1[2], selp);
        }
        short8 B10 = __builtin_bit_cast(short8, pk2);
        short8 B11 = __builtin_bit_cast(short8, pk3);
        acc0 = __builtin_amdgcn_mfma_f32_32x32x16_bf16(A1, B10, acc0, 0, 0, 0);
        acc1 = __builtin_amdgcn_mfma_f32_32x32x16_bf16(A1, B11, acc1, 0, 0, 0);
    }

    // ---- bias + relu -> bf16 -> swizzled LDS rows<20 (reuses [0..1280)) ----
    const float b1v0 = b1[c];
    const float b1v1 = b1[32 + c];
    #pragma unroll
    for (int r = 0; r < 12; ++r) {
        const int row = (r & 3) + 8 * (r >> 2) + 4 * g;
        if (row < KN) {
            const int ch0 = (c >> 3) ^ (row & 7);
            const int ch1 = (4 + (c >> 3)) ^ (row & 7);
            buf[w][row * DD + ch0 * 8 + (c & 7)] = f2bf(fmaxf(acc0[r] + b1v0, 0.f));
            buf[w][row * DD + ch1 * 8 + (c & 7)] = f2bf(fmaxf(acc1[r] + b1v1, 0.f));
        }
    }

    // ---- layer2 MFMA: h2(20x32) = h1(20x64) @ w2(64x32), 4 K-steps ----
    const int ar = (c < KN) ? c : 0;       // clamp A row (rows>=20 don't-care)
    f32x16 c2 = {};
    #pragma unroll
    for (int t = 0; t < 4; ++t) {
        const int chunk = (2 * t + g) ^ (ar & 7);
        short8 A = *(const short8*)&buf[w][ar * DD + chunk * 8];
        short8 B = *(const short8*)&w2b[(size_t)(((t * 2 + g) * 32 + c)) * 8];
        c2 = __builtin_amdgcn_mfma_f32_32x32x16_bf16(A, B, c2, 0, 0, 0);
    }

    // ---- layer3: bias+relu, *w3, DPP-sum over 32 cols, sigmoid, mean ----
    const float b2v = b2[c];
    const float w3v = w3[c];
    const float b3v = b3[0];
    float sum = 0.f;
    #pragma unroll
    for (int r = 0; r < 12; ++r) {
        float h2v = fmaxf(c2[r] + b2v, 0.f);
        float p = dpp_sum32(h2v * w3v);            // valid in lanes 31 / 63
        float logit = p + b3v;
        if (g == 0 || r < 8)                       // valid rows: g0 12, g1 8 (=20)
            sum += 1.f / (1.f + __expf(-logit));
    }
    sum += __shfl_xor(sum, 32);                    // lane31 += lane63's sum
    if (lane == 31) out[b] = sum * (1.f / KN);
}

extern "C" void kernel_launch(void* const* d_in, const int* in_sizes, int n_in,
                              void* d_out, int out_size, void* d_ws, size_t ws_size,
                              hipStream_t stream) {
    const int*   user_idxs       = (const int*)  d_in[0];
    const int*   item_idxs       = (const int*)  d_in[1];
    const int*   user_idx_tensor = (const int*)  d_in[2];
    const float* user_scr_tensor = (const float*)d_in[3];
    const int*   item_idx_tensor = (const int*)  d_in[4];
    const float* item_scr_tensor = (const float*)d_in[5];
    const float* user_emb        = (const float*)d_in[6];
    const float* item_emb        = (const float*)d_in[7];
    const float* w1 = (const float*)d_in[8];
    const float* b1 = (const float*)d_in[9];
    const float* w2 = (const float*)d_in[10];
    const float* b2 = (const float*)d_in[11];
    const float* w3 = (const float*)d_in[12];
    const float* b3 = (const float*)d_in[13];
    float* out = (float*)d_out;

    const int Bn = in_sizes[0];

    // ws: Yu bf16[100000*64] | Yi bf16[50000*64] | w2b u16[2048] | sbu | sbi
    bf16*   Yu  = (bf16*)d_ws;
    bf16*   Yi  = Yu + (size_t)NUSERS * DD;
    ushort* w2b = (ushort*)(Yi + (size_t)NITEMS * DD);
    ushort* sbu = w2b + 2048;
    ushort* sbi = sbu + (size_t)NUSERS * SROW;

    const size_t need = (size_t)(NUSERS + NITEMS) * DD * 2 + 2048 * 2
                      + (size_t)(NUSERS + NITEMS) * SROW * 2;
    const bool big = ws_size >= need;

    precompute_Y<<<NBY, 256, 0, stream>>>(
        user_emb, item_emb, w1, w2, user_scr_tensor, item_scr_tensor,
        Yu, Yi, w2b, sbu, sbi, big ? 1 : 0);

    const int grid = (Bn + WPB - 1) / WPB;
    if (big)
        cnn_main<true><<<grid, 256, 0, stream>>>(
            user_idxs, item_idxs, user_idx_tensor, user_scr_tensor, sbu,
            item_idx_tensor, item_scr_tensor, sbi, Yu, Yi,
            b1, w2b, b2, w3, b3, out, Bn);
    else
        cnn_main<false><<<grid, 256, 0, stream>>>(
            user_idxs, item_idxs, user_idx_tensor, user_scr_tensor, sbu,
            item_idx_tensor, item_scr_tensor, sbi, Yu, Yi,
            b1, w2b, b2, w3, b3, out, Bn);
}